// Round 5
// baseline (980.212 us; speedup 1.0000x reference)
//
#include <hip/hip_runtime.h>
#include <math.h>

typedef short short8 __attribute__((ext_vector_type(8)));
typedef float f32x4 __attribute__((ext_vector_type(4)));

#define EPSF 1e-5f

union FragU {
    uint4 q;
    unsigned u[4];
    short8 v;
};

// --- bf16 truncation packing via v_perm_b32 ---
__device__ __forceinline__ unsigned pack_trunc2(float lo_val, float hi_val) {
    return __builtin_amdgcn_perm(__float_as_uint(hi_val), __float_as_uint(lo_val), 0x07060302u);
}
__device__ __forceinline__ float trunc_bf(float x) {
    return __uint_as_float(__float_as_uint(x) & 0xFFFF0000u);
}

// ---------------- LN over 128, writes TRANSPOSED xnT[i][m] (m padded to 1792) ----------------
__global__ void ln1_kernel(const float* __restrict__ x, const float* __restrict__ w,
                           const float* __restrict__ b, float* __restrict__ xnT) {
    int r = blockIdx.x;
    int t = threadIdx.x;
    const float* row = x + (size_t)r * 128;
    float v0 = row[t], v1 = row[t + 64];
    float s = v0 + v1, q = v0 * v0 + v1 * v1;
    #pragma unroll
    for (int off = 32; off > 0; off >>= 1) {
        s += __shfl_down(s, off);
        q += __shfl_down(q, off);
    }
    s = __shfl(s, 0); q = __shfl(q, 0);
    float mu = s * (1.f / 128.f);
    float var = q * (1.f / 128.f) - mu * mu;
    float rs = rsqrtf(var + EPSF);
    xnT[(size_t)t * 1792 + r]        = (v0 - mu) * rs * w[t]      + b[t];
    xnT[(size_t)(t + 64) * 1792 + r] = (v1 - mu) * rs * w[t + 64] + b[t + 64];
}

// load 16 g-pairs (fp32 cos & sin coeff values) starting at g0 from p0/p1
__device__ __forceinline__ void load_chunk16(const float* __restrict__ p0,
                                             const float* __restrict__ p1,
                                             int g0, bool on, float* w0, float* w1) {
    #pragma unroll
    for (int k4 = 0; k4 < 4; ++k4) {
        int g = g0 + k4 * 4;
        if (on && g + 4 <= 300) {
            float4 a = *(const float4*)(p0 + g);
            float4 bb = *(const float4*)(p1 + g);
            w0[k4*4+0] = a.x;  w0[k4*4+1] = a.y;  w0[k4*4+2] = a.z;  w0[k4*4+3] = a.w;
            w1[k4*4+0] = bb.x; w1[k4*4+1] = bb.y; w1[k4*4+2] = bb.z; w1[k4*4+3] = bb.w;
        } else {
            #pragma unroll
            for (int e = 0; e < 4; ++e) {
                int gg = g + e;
                bool ok = on && (gg < 300);
                w0[k4*4+e] = ok ? p0[gg] : 0.f;
                w1[k4*4+e] = ok ? p1[gg] : 0.f;
            }
        }
    }
}

// ---------------- fc1: split-bf16 MFMA GEMM. M=1792(pad), N=256, K=128*608 ----------------
// grid (2 ntiles, 14 mtiles of 128, ks1), block 256 (4 waves). Wave: m=32, n=128.
__launch_bounds__(256)
__global__ void fc1_kernel(const float* __restrict__ xnT, const float* __restrict__ coeffs,
                           float* __restrict__ part1, int KS) {
    const int nt = blockIdx.x;
    const int mt = blockIdx.y;
    const int ks = blockIdx.z;
    const int i0 = (ks * 128) / KS, i1 = ((ks + 1) * 128) / KS;
    const int t = threadIdx.x;
    const int wv = t >> 6, ln = t & 63;
    const int q = ln >> 4, col = ln & 15;
    const int mrow = mt * 128 + wv * 32;

    __shared__ unsigned bhi[128 * 36];
    __shared__ unsigned blo[128 * 36];

    const float* c0 = coeffs;                                   // [256][128][300]
    const float* c1 = coeffs + (size_t)256 * 128 * 300;

    f32x4 acc[2][8] = {};

    // staging role: thread -> (row o_loc, 16 g-slots starting at j0)
    const int o_loc = t >> 1;
    const int j0 = (t & 1) * 16;
    const int og = nt * 128 + o_loc;
    const size_t prow = (size_t)og * 128;    // row base (in i units)

    const int mg0 = mrow + col, mg1 = mrow + 16 + col;
    const bool m0ok = (mg0 < 1568), m1ok = (mg1 < 1568);

    // ---- prologue: prefetch zu(i0) and chunk(i0, c=0) ----
    float zu0 = m0ok ? xnT[(size_t)i0 * 1792 + mg0] : 0.f;
    float zu1 = m1ok ? xnT[(size_t)i0 * 1792 + mg1] : 0.f;
    float w0[16], w1[16];
    load_chunk16(c0 + (prow + i0) * 300, c1 + (prow + i0) * 300, j0, true, w0, w1);

    for (int i = i0; i < i1; ++i) {
        // prefetch next i's zu (used next iteration; ~10 chunks in flight)
        float nz0 = 0.f, nz1 = 0.f;
        if (i + 1 < i1) {
            if (m0ok) nz0 = xnT[(size_t)(i + 1) * 1792 + mg0];
            if (m1ok) nz1 = xnT[(size_t)(i + 1) * 1792 + mg1];
        }
        for (int c = 0; c < 10; ++c) {       // k-chunks of 32 g-pairs; this thread covers 16
            __syncthreads();
            {   // pack + write prefetched regs to LDS
                unsigned hw[16], lw[16];
                #pragma unroll
                for (int k = 0; k < 16; ++k) {
                    hw[k] = pack_trunc2(w0[k], w1[k]);
                    lw[k] = pack_trunc2(w0[k] - trunc_bf(w0[k]), w1[k] - trunc_bf(w1[k]));
                }
                int base = o_loc * 36 + j0;
                *(uint4*)&bhi[base]      = make_uint4(hw[0], hw[1], hw[2], hw[3]);
                *(uint4*)&bhi[base + 4]  = make_uint4(hw[4], hw[5], hw[6], hw[7]);
                *(uint4*)&bhi[base + 8]  = make_uint4(hw[8], hw[9], hw[10], hw[11]);
                *(uint4*)&bhi[base + 12] = make_uint4(hw[12], hw[13], hw[14], hw[15]);
                *(uint4*)&blo[base]      = make_uint4(lw[0], lw[1], lw[2], lw[3]);
                *(uint4*)&blo[base + 4]  = make_uint4(lw[4], lw[5], lw[6], lw[7]);
                *(uint4*)&blo[base + 8]  = make_uint4(lw[8], lw[9], lw[10], lw[11]);
                *(uint4*)&blo[base + 12] = make_uint4(lw[12], lw[13], lw[14], lw[15]);
            }
            __syncthreads();
            // issue loads for the NEXT chunk now; they stay in flight during compute
            {
                int ni = (c == 9) ? i + 1 : i;
                int ncg = (c == 9) ? 0 : (c + 1) * 32;
                if (ni < i1)
                    load_chunk16(c0 + (prow + ni) * 300, c1 + (prow + ni) * 300,
                                 ncg + j0, true, w0, w1);
            }
            // compute chunk c
            #pragma unroll
            for (int h = 0; h < 2; ++h) {
                FragU ah0, al0, ah1, al1;
                int g0 = c * 32 + h * 16 + q * 4;
                #pragma unroll
                for (int d = 0; d < 4; ++d) {
                    float kf = (float)(g0 + d + 1);
                    float a0 = zu0 * kf, a1 = zu1 * kf;
                    float cv0 = __cosf(a0), sv0 = __sinf(a0);
                    float cv1 = __cosf(a1), sv1 = __sinf(a1);
                    ah0.u[d] = pack_trunc2(cv0, sv0);
                    al0.u[d] = pack_trunc2(cv0 - trunc_bf(cv0), sv0 - trunc_bf(sv0));
                    ah1.u[d] = pack_trunc2(cv1, sv1);
                    al1.u[d] = pack_trunc2(cv1 - trunc_bf(cv1), sv1 - trunc_bf(sv1));
                }
                #pragma unroll
                for (int un = 0; un < 8; ++un) {
                    int row = un * 16 + col;
                    FragU bh, bl;
                    bh.q = *(const uint4*)&bhi[row * 36 + h * 16 + q * 4];
                    bl.q = *(const uint4*)&blo[row * 36 + h * 16 + q * 4];
                    acc[0][un] = __builtin_amdgcn_mfma_f32_16x16x32_bf16(ah0.v, bh.v, acc[0][un], 0, 0, 0);
                    acc[0][un] = __builtin_amdgcn_mfma_f32_16x16x32_bf16(ah0.v, bl.v, acc[0][un], 0, 0, 0);
                    acc[0][un] = __builtin_amdgcn_mfma_f32_16x16x32_bf16(al0.v, bh.v, acc[0][un], 0, 0, 0);
                    acc[1][un] = __builtin_amdgcn_mfma_f32_16x16x32_bf16(ah1.v, bh.v, acc[1][un], 0, 0, 0);
                    acc[1][un] = __builtin_amdgcn_mfma_f32_16x16x32_bf16(ah1.v, bl.v, acc[1][un], 0, 0, 0);
                    acc[1][un] = __builtin_amdgcn_mfma_f32_16x16x32_bf16(al1.v, bh.v, acc[1][un], 0, 0, 0);
                }
            }
        }
        zu0 = nz0; zu1 = nz1;
    }
    #pragma unroll
    for (int um = 0; um < 2; ++um) {
        int mbase = mrow + um * 16 + q * 4;
        #pragma unroll
        for (int un = 0; un < 8; ++un) {
            int o = nt * 128 + un * 16 + col;
            #pragma unroll
            for (int r = 0; r < 4; ++r)
                part1[((size_t)ks * 1792 + mbase + r) * 256 + o] = acc[um][un][r];
        }
    }
}

// ---------------- reduce ks1 planes + fc1_bias, then LN over 256 -> h1n ----------------
__global__ void reduce1_ln2(const float* __restrict__ part1, const float* __restrict__ bias,
                            const float* __restrict__ w, const float* __restrict__ b,
                            float* __restrict__ h1n, int KS) {
    int r = blockIdx.x;
    int t = threadIdx.x;
    float v = bias[t];
    for (int ks = 0; ks < KS; ++ks) v += part1[((size_t)ks * 1792 + r) * 256 + t];
    float s = v, q = v * v;
    #pragma unroll
    for (int off = 32; off > 0; off >>= 1) {
        s += __shfl_down(s, off);
        q += __shfl_down(q, off);
    }
    __shared__ float ss[4], qq[4];
    int wid = t >> 6;
    if ((t & 63) == 0) { ss[wid] = s; qq[wid] = q; }
    __syncthreads();
    float S = ss[0] + ss[1] + ss[2] + ss[3];
    float Q = qq[0] + qq[1] + qq[2] + qq[3];
    float mu = S * (1.f / 256.f);
    float var = Q * (1.f / 256.f) - mu * mu;
    float rs = rsqrtf(var + EPSF);
    h1n[(size_t)r * 256 + t] = (v - mu) * rs * w[t] + b[t];
}

// ---------------- fc2: bf16 MFMA GEMM. M=2048 (b*256+c), N=224(pad of 196), K=196*608 ----------------
// grid (2 ntiles, 16 mtiles of 128, ks2), block 256 (4 waves). Wave: m=32, n=112.
__launch_bounds__(256)
__global__ void fc2_kernel(const float* __restrict__ h1n, const float* __restrict__ coeffs,
                           float* __restrict__ part2, int KS) {
    const int nt = blockIdx.x;
    const int mt = blockIdx.y;           // b = mt>>1, c-base = (mt&1)*128
    const int ks = blockIdx.z;
    const int i0 = (ks * 196) / KS, i1 = ((ks + 1) * 196) / KS;
    const int t = threadIdx.x;
    const int wv = t >> 6, ln = t & 63;
    const int q = ln >> 4, col = ln & 15;
    const int b = mt >> 1;
    const int cb = (mt & 1) * 128 + wv * 32;

    __shared__ unsigned bs[112 * 36];

    const float* c0 = coeffs;                                   // [196][196][300]
    const float* c1 = coeffs + (size_t)196 * 196 * 300;

    f32x4 acc[2][7] = {};

    const int o_loc = t >> 1;
    const int j0 = (t & 1) * 16;
    const int og = nt * 112 + o_loc;
    const bool stage_on = (t < 224) && (og < 196);
    const size_t prow = (size_t)og * 196;

    // ---- prologue ----
    float zu0 = h1n[((size_t)b * 196 + i0) * 256 + cb + col];
    float zu1 = h1n[((size_t)b * 196 + i0) * 256 + cb + 16 + col];
    float w0[16], w1[16];
    load_chunk16(c0 + (prow + i0) * 300, c1 + (prow + i0) * 300, j0, stage_on, w0, w1);

    for (int i = i0; i < i1; ++i) {
        float nz0 = 0.f, nz1 = 0.f;
        if (i + 1 < i1) {
            nz0 = h1n[((size_t)b * 196 + i + 1) * 256 + cb + col];
            nz1 = h1n[((size_t)b * 196 + i + 1) * 256 + cb + 16 + col];
        }
        for (int c = 0; c < 10; ++c) {
            __syncthreads();
            if (t < 224) {
                unsigned hw[16];
                #pragma unroll
                for (int k = 0; k < 16; ++k) hw[k] = pack_trunc2(w0[k], w1[k]);
                int base = o_loc * 36 + j0;
                *(uint4*)&bs[base]      = make_uint4(hw[0], hw[1], hw[2], hw[3]);
                *(uint4*)&bs[base + 4]  = make_uint4(hw[4], hw[5], hw[6], hw[7]);
                *(uint4*)&bs[base + 8]  = make_uint4(hw[8], hw[9], hw[10], hw[11]);
                *(uint4*)&bs[base + 12] = make_uint4(hw[12], hw[13], hw[14], hw[15]);
            }
            __syncthreads();
            {
                int ni = (c == 9) ? i + 1 : i;
                int ncg = (c == 9) ? 0 : (c + 1) * 32;
                if (ni < i1)
                    load_chunk16(c0 + (prow + ni) * 300, c1 + (prow + ni) * 300,
                                 ncg + j0, stage_on, w0, w1);
            }
            #pragma unroll
            for (int h = 0; h < 2; ++h) {
                FragU a0, a1;
                int g0 = c * 32 + h * 16 + q * 4;
                #pragma unroll
                for (int d = 0; d < 4; ++d) {
                    float kf = (float)(g0 + d + 1);
                    float aa0 = zu0 * kf, aa1 = zu1 * kf;
                    a0.u[d] = pack_trunc2(__cosf(aa0), __sinf(aa0));
                    a1.u[d] = pack_trunc2(__cosf(aa1), __sinf(aa1));
                }
                #pragma unroll
                for (int un = 0; un < 7; ++un) {
                    int row = un * 16 + col;
                    FragU bh;
                    bh.q = *(const uint4*)&bs[row * 36 + h * 16 + q * 4];
                    acc[0][un] = __builtin_amdgcn_mfma_f32_16x16x32_bf16(a0.v, bh.v, acc[0][un], 0, 0, 0);
                    acc[1][un] = __builtin_amdgcn_mfma_f32_16x16x32_bf16(a1.v, bh.v, acc[1][un], 0, 0, 0);
                }
            }
        }
        zu0 = nz0; zu1 = nz1;
    }
    #pragma unroll
    for (int um = 0; um < 2; ++um) {
        int mbase = mt * 128 + wv * 32 + um * 16 + q * 4;
        #pragma unroll
        for (int un = 0; un < 7; ++un) {
            int o = nt * 112 + un * 16 + col;
            #pragma unroll
            for (int r = 0; r < 4; ++r)
                part2[((size_t)ks * 2048 + mbase + r) * 224 + o] = acc[um][un][r];
        }
    }
}

// ---------------- reduce ks2 planes + fc2_bias -> out[b][o][c] ----------------
__global__ void reduce2_kernel(const float* __restrict__ part2, const float* __restrict__ bias,
                               float* __restrict__ out, int KS) {
    int ot = blockIdx.x;
    int b  = blockIdx.y;
    int t  = threadIdx.x;
    float s[16] = {};
    for (int ks = 0; ks < KS; ++ks) {
        const float* p = part2 + ((size_t)ks * 2048 + b * 256 + t) * 224 + ot * 16;
        #pragma unroll
        for (int j4 = 0; j4 < 4; ++j4) {
            float4 a = *(const float4*)(p + j4 * 4);
            s[j4 * 4 + 0] += a.x; s[j4 * 4 + 1] += a.y;
            s[j4 * 4 + 2] += a.z; s[j4 * 4 + 3] += a.w;
        }
    }
    #pragma unroll
    for (int j = 0; j < 16; ++j) {
        int o = ot * 16 + j;
        if (o < 196)
            out[((size_t)b * 196 + o) * 256 + t] = s[j] + bias[o];
    }
}

extern "C" void kernel_launch(void* const* d_in, const int* in_sizes, int n_in,
                              void* d_out, int out_size, void* d_ws, size_t ws_size,
                              hipStream_t stream) {
    const float* x       = (const float*)d_in[0];
    const float* ln1w    = (const float*)d_in[1];
    const float* ln1b    = (const float*)d_in[2];
    const float* fc1c    = (const float*)d_in[3];
    const float* fc1bias = (const float*)d_in[4];
    const float* ln2w    = (const float*)d_in[5];
    const float* ln2b    = (const float*)d_in[6];
    const float* fc2c    = (const float*)d_in[7];
    const float* fc2bias = (const float*)d_in[8];
    float* out = (float*)d_out;

    const size_t xnT_elems = (size_t)128 * 1792;
    const size_t h1n_elems = 401408;
    const size_t plane     = 458752;                // 1792*256 == 2048*224
    const size_t fixedB    = (xnT_elems + h1n_elems) * 4;

    int ks1 = 16, ks2 = 14;
    {
        long long planes = (ws_size > fixedB) ? (long long)((ws_size - fixedB) / (plane * 4)) : 2;
        if (planes < 2) planes = 2;
        if (planes < 30) {
            ks1 = (int)(planes / 2);
            ks2 = (int)(planes - ks1);
            if (ks1 < 1) ks1 = 1;
            if (ks2 < 1) ks2 = 1;
            if (ks1 > 16) ks1 = 16;
            if (ks2 > 14) ks2 = 14;
        }
    }

    float* xnT   = (float*)d_ws;
    float* h1n   = xnT + xnT_elems;
    float* part1 = h1n + h1n_elems;
    float* part2 = part1 + (size_t)ks1 * plane;

    ln1_kernel<<<1568, 64, 0, stream>>>(x, ln1w, ln1b, xnT);
    fc1_kernel<<<dim3(2, 14, ks1), 256, 0, stream>>>(xnT, fc1c, part1, ks1);
    reduce1_ln2<<<1568, 256, 0, stream>>>(part1, fc1bias, ln2w, ln2b, h1n, ks1);
    fc2_kernel<<<dim3(2, 16, ks2), 256, 0, stream>>>(h1n, fc2c, part2, ks2);
    reduce2_kernel<<<dim3(13, 8), 256, 0, stream>>>(part2, fc2bias, out, ks2);
}

// Round 6
// 738.975 us; speedup vs baseline: 1.3264x; 1.3264x over previous
//
#include <hip/hip_runtime.h>
#include <math.h>

typedef short short8 __attribute__((ext_vector_type(8)));
typedef float f32x4 __attribute__((ext_vector_type(4)));

#define EPSF 1e-5f

union FragU { uint4 q; unsigned u[4]; short8 v; };

// bf16 truncation pack: (trunc(hi)<<16)|trunc(lo) in one v_perm
__device__ __forceinline__ unsigned pack_trunc2(float lo_val, float hi_val) {
    return __builtin_amdgcn_perm(__float_as_uint(hi_val), __float_as_uint(lo_val), 0x07060302u);
}
__device__ __forceinline__ float trunc_bf(float x) {
    return __uint_as_float(__float_as_uint(x) & 0xFFFF0000u);
}

// ---------------- LN over 128, writes TRANSPOSED xnT[i][m], m padded to 1792 ----------------
__global__ void ln1_kernel(const float* __restrict__ x, const float* __restrict__ w,
                           const float* __restrict__ b, float* __restrict__ xnT) {
    int r = blockIdx.x;
    int t = threadIdx.x;
    const float* row = x + (size_t)r * 128;
    float v0 = row[t], v1 = row[t + 64];
    float s = v0 + v1, q = v0 * v0 + v1 * v1;
    #pragma unroll
    for (int off = 32; off > 0; off >>= 1) {
        s += __shfl_down(s, off);
        q += __shfl_down(q, off);
    }
    s = __shfl(s, 0); q = __shfl(q, 0);
    float mu = s * (1.f / 128.f);
    float var = q * (1.f / 128.f) - mu * mu;
    float rs = rsqrtf(var + EPSF);
    xnT[(size_t)t * 1792 + r]        = (v0 - mu) * rs * w[t]      + b[t];
    xnT[(size_t)(t + 64) * 1792 + r] = (v1 - mu) * rs * w[t + 64] + b[t + 64];
}

// ---------------- fc1: split-bf16 MFMA. block: m-tile 256 (4 waves x m64), n-tile 128 ----------------
// grid (2, 7, ks1=32), 4 i per block. Atomic k-split into h1.
__launch_bounds__(256)
__global__ void fc1_kernel(const float* __restrict__ xnT, const float* __restrict__ coeffs,
                           float* __restrict__ h1, int KS) {
    const int nt = blockIdx.x;
    const int mt = blockIdx.y;
    const int ks = blockIdx.z;
    const int i0 = (ks * 128) / KS, i1 = ((ks + 1) * 128) / KS;
    const int t = threadIdx.x;
    const int wv = t >> 6, ln = t & 63;
    const int q = ln >> 4, col = ln & 15;
    const int mwrow = mt * 256 + wv * 64;

    __shared__ unsigned bhi[128 * 36];
    __shared__ unsigned blo[128 * 36];

    const float* c0 = coeffs;                               // [256][128][300]
    const float* c1 = coeffs + (size_t)256 * 128 * 300;

    f32x4 acc[4][8] = {};

    const int srow = t >> 1;            // staging row 0..127
    const int j0 = (t & 1) * 16;
    const int og = nt * 128 + srow;
    const size_t prow = (size_t)og * 128;

    for (int i = i0; i < i1; ++i) {
        float zu[4];
        #pragma unroll
        for (int mf = 0; mf < 4; ++mf) {
            int m = mwrow + mf * 16 + col;
            zu[mf] = (m < 1568) ? xnT[(size_t)i * 1792 + m] : 0.f;
        }
        const float* p0 = c0 + (prow + i) * 300;
        const float* p1 = c1 + (prow + i) * 300;

        for (int c = 0; c < 10; ++c) {
            __syncthreads();
            {
                unsigned hw[16], lw[16];
                #pragma unroll
                for (int k4 = 0; k4 < 4; ++k4) {
                    int g = c * 32 + j0 + k4 * 4;
                    float w0[4], w1[4];
                    if (g + 4 <= 300) {
                        float4 a = *(const float4*)(p0 + g);
                        float4 bb = *(const float4*)(p1 + g);
                        w0[0]=a.x; w0[1]=a.y; w0[2]=a.z; w0[3]=a.w;
                        w1[0]=bb.x; w1[1]=bb.y; w1[2]=bb.z; w1[3]=bb.w;
                    } else {
                        #pragma unroll
                        for (int e = 0; e < 4; ++e) {
                            int gg = g + e; bool ok = gg < 300;
                            w0[e] = ok ? p0[gg] : 0.f;
                            w1[e] = ok ? p1[gg] : 0.f;
                        }
                    }
                    #pragma unroll
                    for (int e = 0; e < 4; ++e) {
                        hw[k4*4+e] = pack_trunc2(w0[e], w1[e]);
                        lw[k4*4+e] = pack_trunc2(w0[e]-trunc_bf(w0[e]), w1[e]-trunc_bf(w1[e]));
                    }
                }
                int base = srow * 36 + j0;
                *(uint4*)&bhi[base]      = make_uint4(hw[0], hw[1], hw[2], hw[3]);
                *(uint4*)&bhi[base + 4]  = make_uint4(hw[4], hw[5], hw[6], hw[7]);
                *(uint4*)&bhi[base + 8]  = make_uint4(hw[8], hw[9], hw[10], hw[11]);
                *(uint4*)&bhi[base + 12] = make_uint4(hw[12], hw[13], hw[14], hw[15]);
                *(uint4*)&blo[base]      = make_uint4(lw[0], lw[1], lw[2], lw[3]);
                *(uint4*)&blo[base + 4]  = make_uint4(lw[4], lw[5], lw[6], lw[7]);
                *(uint4*)&blo[base + 8]  = make_uint4(lw[8], lw[9], lw[10], lw[11]);
                *(uint4*)&blo[base + 12] = make_uint4(lw[12], lw[13], lw[14], lw[15]);
            }
            __syncthreads();
            #pragma unroll
            for (int h = 0; h < 2; ++h) {
                FragU ah[4], al[4];
                #pragma unroll
                for (int mf = 0; mf < 4; ++mf) {
                    #pragma unroll
                    for (int d = 0; d < 4; ++d) {
                        float kf = (float)(c * 32 + h * 16 + q * 4 + d + 1);
                        float a = zu[mf] * kf;
                        float cv = __cosf(a), sv = __sinf(a);
                        ah[mf].u[d] = pack_trunc2(cv, sv);
                        al[mf].u[d] = pack_trunc2(cv - trunc_bf(cv), sv - trunc_bf(sv));
                    }
                }
                #pragma unroll
                for (int nf = 0; nf < 8; ++nf) {
                    int addr = (nf * 16 + col) * 36 + h * 16 + q * 4;
                    FragU bh, bl;
                    bh.q = *(const uint4*)&bhi[addr];
                    bl.q = *(const uint4*)&blo[addr];
                    #pragma unroll
                    for (int mf = 0; mf < 4; ++mf) {
                        acc[mf][nf] = __builtin_amdgcn_mfma_f32_16x16x32_bf16(ah[mf].v, bh.v, acc[mf][nf], 0, 0, 0);
                        acc[mf][nf] = __builtin_amdgcn_mfma_f32_16x16x32_bf16(ah[mf].v, bl.v, acc[mf][nf], 0, 0, 0);
                        acc[mf][nf] = __builtin_amdgcn_mfma_f32_16x16x32_bf16(al[mf].v, bh.v, acc[mf][nf], 0, 0, 0);
                    }
                }
            }
        }
    }
    // epilogue: atomic k-split accumulation (1568 % 16 == 0 so frag is all-in or all-out)
    #pragma unroll
    for (int mf = 0; mf < 4; ++mf) {
        if (mwrow + mf * 16 >= 1568) continue;
        int mbase = mwrow + mf * 16 + q * 4;
        #pragma unroll
        for (int nf = 0; nf < 8; ++nf) {
            int o = nt * 128 + nf * 16 + col;
            #pragma unroll
            for (int r = 0; r < 4; ++r)
                atomicAdd(&h1[(size_t)(mbase + r) * 256 + o], acc[mf][nf][r]);
        }
    }
}

// ---------------- LN over 256 of (h1 + fc1_bias) -> h1n ----------------
__global__ void ln2_kernel(const float* __restrict__ h1, const float* __restrict__ bias,
                           const float* __restrict__ w, const float* __restrict__ b,
                           float* __restrict__ h1n) {
    int r = blockIdx.x;
    int t = threadIdx.x;
    float v = h1[(size_t)r * 256 + t] + bias[t];
    float s = v, q = v * v;
    #pragma unroll
    for (int off = 32; off > 0; off >>= 1) {
        s += __shfl_down(s, off);
        q += __shfl_down(q, off);
    }
    __shared__ float ss[4], qq[4];
    int wid = t >> 6;
    if ((t & 63) == 0) { ss[wid] = s; qq[wid] = q; }
    __syncthreads();
    float S = ss[0] + ss[1] + ss[2] + ss[3];
    float Q = qq[0] + qq[1] + qq[2] + qq[3];
    float mu = S * (1.f / 256.f);
    float var = Q * (1.f / 256.f) - mu * mu;
    float rs = rsqrtf(var + EPSF);
    h1n[(size_t)r * 256 + t] = (v - mu) * rs * w[t] + b[t];
}

__device__ __forceinline__ void cmul(float& xr, float& xi, float br, float bi) {
    float nr = xr * br - xi * bi;
    float ni = xr * bi + xi * br;
    xr = nr; xi = ni;
}

// ---------------- fc2: bf16 MFMA. block: m-tile 256 (= one b, 4 waves x c64), n-tile 128 ----------------
// grid (2, 8, ks2=28), 7 i per block. A via complex-rotation recurrence. Atomic k-split into out.
__launch_bounds__(256)
__global__ void fc2_kernel(const float* __restrict__ h1n, const float* __restrict__ coeffs,
                           float* __restrict__ out, int KS) {
    const int nt = blockIdx.x;
    const int b  = blockIdx.y;
    const int ks = blockIdx.z;
    const int i0 = (ks * 196) / KS, i1 = ((ks + 1) * 196) / KS;
    const int t = threadIdx.x;
    const int wv = t >> 6, ln = t & 63;
    const int q = ln >> 4, col = ln & 15;
    const int cwb = wv * 64;

    __shared__ unsigned bs[128 * 36];

    const float* d0 = coeffs;                               // [196][196][300]
    const float* d1 = coeffs + (size_t)196 * 196 * 300;

    f32x4 acc[4][8] = {};

    const int srow = t >> 1;
    const int j0 = (t & 1) * 16;
    const int og = nt * 128 + srow;
    const bool son = (og < 196);
    const size_t prow = (size_t)og * 196;

    for (int i = i0; i < i1; ++i) {
        // per-m recurrence state: R tracks e^{i n x}, n = current multiplier
        float Rc[4], Rs[4], E1c[4], E1s[4], E13c[4], E13s[4];
        #pragma unroll
        for (int mf = 0; mf < 4; ++mf) {
            float x = h1n[((size_t)b * 196 + i) * 256 + cwb + mf * 16 + col];
            float c1_ = __cosf(x), s1_ = __sinf(x);
            float c2 = c1_*c1_ - s1_*s1_, s2 = 2.f*c1_*s1_;
            float c4 = c2*c2 - s2*s2,    s4 = 2.f*c2*s2;
            float c8 = c4*c4 - s4*s4,    s8 = 2.f*c4*s4;
            float c12 = c8*c4 - s8*s4,   s12 = c8*s4 + s8*c4;
            float c13 = c12*c1_ - s12*s1_, s13 = c12*s1_ + s12*c1_;
            // R = E1^(4q+1)
            float rc = c1_, rs = s1_;
            float m4c = (q & 1) ? c4 : 1.f, m4s = (q & 1) ? s4 : 0.f;
            cmul(rc, rs, m4c, m4s);
            float m8c = (q & 2) ? c8 : 1.f, m8s = (q & 2) ? s8 : 0.f;
            cmul(rc, rs, m8c, m8s);
            Rc[mf] = rc; Rs[mf] = rs;
            E1c[mf] = c1_; E1s[mf] = s1_;
            E13c[mf] = c13; E13s[mf] = s13;
        }
        const float* p0 = d0 + prow * 300 + (size_t)i * 300;
        const float* p1 = d1 + prow * 300 + (size_t)i * 300;

        for (int c = 0; c < 10; ++c) {
            __syncthreads();
            {
                unsigned hw[16];
                #pragma unroll
                for (int k4 = 0; k4 < 4; ++k4) {
                    int g = c * 32 + j0 + k4 * 4;
                    float w0[4], w1[4];
                    if (son && g + 4 <= 300) {
                        float4 a = *(const float4*)(p0 + g);
                        float4 bb = *(const float4*)(p1 + g);
                        w0[0]=a.x; w0[1]=a.y; w0[2]=a.z; w0[3]=a.w;
                        w1[0]=bb.x; w1[1]=bb.y; w1[2]=bb.z; w1[3]=bb.w;
                    } else {
                        #pragma unroll
                        for (int e = 0; e < 4; ++e) {
                            int gg = g + e; bool ok = son && (gg < 300);
                            w0[e] = ok ? p0[gg] : 0.f;
                            w1[e] = ok ? p1[gg] : 0.f;
                        }
                    }
                    #pragma unroll
                    for (int e = 0; e < 4; ++e) hw[k4*4+e] = pack_trunc2(w0[e], w1[e]);
                }
                int base = srow * 36 + j0;
                *(uint4*)&bs[base]      = make_uint4(hw[0], hw[1], hw[2], hw[3]);
                *(uint4*)&bs[base + 4]  = make_uint4(hw[4], hw[5], hw[6], hw[7]);
                *(uint4*)&bs[base + 8]  = make_uint4(hw[8], hw[9], hw[10], hw[11]);
                *(uint4*)&bs[base + 12] = make_uint4(hw[12], hw[13], hw[14], hw[15]);
            }
            __syncthreads();
            #pragma unroll
            for (int h = 0; h < 2; ++h) {
                FragU af[4];
                #pragma unroll
                for (int mf = 0; mf < 4; ++mf) {
                    #pragma unroll
                    for (int d = 0; d < 4; ++d) {
                        af[mf].u[d] = pack_trunc2(Rc[mf], Rs[mf]);
                        if (d < 3) cmul(Rc[mf], Rs[mf], E1c[mf], E1s[mf]);
                        else       cmul(Rc[mf], Rs[mf], E13c[mf], E13s[mf]);
                    }
                }
                #pragma unroll
                for (int nf = 0; nf < 8; ++nf) {
                    int addr = (nf * 16 + col) * 36 + h * 16 + q * 4;
                    FragU bf;
                    bf.q = *(const uint4*)&bs[addr];
                    #pragma unroll
                    for (int mf = 0; mf < 4; ++mf)
                        acc[mf][nf] = __builtin_amdgcn_mfma_f32_16x16x32_bf16(af[mf].v, bf.v, acc[mf][nf], 0, 0, 0);
                }
            }
        }
    }
    #pragma unroll
    for (int mf = 0; mf < 4; ++mf) {
        int cbase = cwb + mf * 16 + q * 4;
        #pragma unroll
        for (int nf = 0; nf < 8; ++nf) {
            int o = nt * 128 + nf * 16 + col;
            if (o < 196) {
                #pragma unroll
                for (int r = 0; r < 4; ++r)
                    atomicAdd(&out[((size_t)b * 196 + o) * 256 + cbase + r], acc[mf][nf][r]);
            }
        }
    }
}

// ---------------- fc2 bias epilogue ----------------
__global__ void bias2_kernel(float* __restrict__ out, const float* __restrict__ bias) {
    int idx = blockIdx.x * 256 + threadIdx.x;
    int o = (idx >> 8) % 196;
    out[idx] += bias[o];
}

extern "C" void kernel_launch(void* const* d_in, const int* in_sizes, int n_in,
                              void* d_out, int out_size, void* d_ws, size_t ws_size,
                              hipStream_t stream) {
    const float* x       = (const float*)d_in[0];
    const float* ln1w    = (const float*)d_in[1];
    const float* ln1b    = (const float*)d_in[2];
    const float* fc1c    = (const float*)d_in[3];
    const float* fc1bias = (const float*)d_in[4];
    const float* ln2w    = (const float*)d_in[5];
    const float* ln2b    = (const float*)d_in[6];
    const float* fc2c    = (const float*)d_in[7];
    const float* fc2bias = (const float*)d_in[8];
    float* out = (float*)d_out;

    float* xnT = (float*)d_ws;              // 128*1792 = 229376
    float* h1  = xnT + 229376;              // 1568*256 = 401408
    float* h1n = h1 + 401408;               // 1568*256

    hipMemsetAsync(h1, 0, (size_t)401408 * 4, stream);
    hipMemsetAsync(d_out, 0, (size_t)401408 * 4, stream);

    const int ks1 = 32, ks2 = 28;
    ln1_kernel<<<1568, 64, 0, stream>>>(x, ln1w, ln1b, xnT);
    fc1_kernel<<<dim3(2, 7, ks1), 256, 0, stream>>>(xnT, fc1c, h1, ks1);
    ln2_kernel<<<1568, 256, 0, stream>>>(h1, fc1bias, ln2w, ln2b, h1n);
    fc2_kernel<<<dim3(2, 8, ks2), 256, 0, stream>>>(h1n, fc2c, out, ks2);
    bias2_kernel<<<1568, 256, 0, stream>>>(out, fc2bias);
}